// Round 11
// baseline (508.916 us; speedup 1.0000x reference)
//
#include <hip/hip_runtime.h>
#include <hip/hip_bf16.h>

#define N_NODES 10000
#define E_TOT   320000

typedef __attribute__((ext_vector_type(8))) short short8;
typedef __attribute__((ext_vector_type(4))) short s16x4;
typedef __attribute__((ext_vector_type(4))) float f32x4;

// ---- workspace byte offsets (16B-aligned) ----
#define HIST_OFF    0u            // N int (zeroed)
#define FILL_OFF    40000u        // N int (zeroed)
#define ZERO_BYTES  80000u        // memset [0, here)
#define ROWPTR_OFF  80000u        // (N+1) int
#define PERM_OFF    120064u       // E int (fallback path only)
#define PSRC_OFF    1400064u      // E int
#define CN_OFF      2680064u      // N*544 shorts
#define QARR_OFF    13560064u     // N*208 shorts
#define QV_OFF      17720064u     // N*96 bf16
#define WHV4_OFF    19640064u     // 128 f32
#define WBIG_OFF    19640576u     // 256*672 bf16
#define NSBF_OFF    19984640u     // N*256 bf16
#define ANSB_OFF    25104640u     // N*256 bf16
#define EAB_OFF     30224640u     // N*160 bf16
#define AP_OFF      33424640u     // N*204 f32
#define AEV_OFF     41584640u     // N*12 f32
#define FLAGS_OFF   42064640u     // 2 ints
#define EVS_OFF     42064704u     // E*76 bf16 rows [es(64)|ev(12)] in pos order (seq path)
#define EVS_BYTES   48640000u
// NodeS (N*256 f32) aliases [PERM_OFF, ...): perm/psrc/CN dead by node_gemm.
#define NODES_OFF   120064u

union BfS { __hip_bfloat16 h; short s; };
__device__ __forceinline__ short f2bf(float x) { BfS u; u.h = __float2bfloat16(x); return u.s; }
__device__ __forceinline__ float bf(short x) { BfS u; u.s = x; return __bfloat162float(u.h); }
__device__ __forceinline__ float bflo(unsigned u) { return __uint_as_float(u << 16); }
__device__ __forceinline__ float bfhi(unsigned u) { return __uint_as_float(u & 0xffff0000u); }
__device__ __forceinline__ float ldin(const void* p, int f32m, long i) {
  return f32m ? ((const float*)p)[i] : __bfloat162float(((const __hip_bfloat16*)p)[i]);
}
__device__ __forceinline__ int get_ei(const void* p, int i64m, long i) {
  return i64m ? (int)(((const long long*)p)[i]) : ((const int*)p)[i];
}

// ---------------------------------------------------------------------------
// hist_det: per-block i64m self-detect + hist atomic; block 0 writes flags;
// all blocks also zero the AEV accumulator region (grid-stride).
// ---------------------------------------------------------------------------
__global__ __launch_bounds__(256) void hist_det(
    const void* __restrict__ edge_index, const unsigned short* __restrict__ ns_u16,
    int* __restrict__ hist, int* __restrict__ flags)
{
  const int tid = threadIdx.x;
  const int* ei = (const int*)edge_index;
  int nz = (ei[2 * tid + 1] != 0) ? 1 : 0;
  unsigned long long m = __ballot(nz);
  __shared__ int cnt4[4];
  if ((tid & 63) == 0) cnt4[tid >> 6] = __popcll(m);
  __syncthreads();
  const int i64m = (cnt4[0] + cnt4[1] + cnt4[2] + cnt4[3]) < 16 ? 1 : 0;
  int e = blockIdx.x * 256 + tid;
  int dst = get_ei(edge_index, i64m, (long)E_TOT + e);
  atomicAdd(&hist[dst], 1);
  if (blockIdx.x == 0) {
    __shared__ int cf;
    if (tid == 0) cf = 0;
    __syncthreads();
    int c1 = 0;
    for (int i = tid; i < 8192; i += 256) {
      unsigned ex = (ns_u16[2 * i] >> 7) & 0xFF;
      if (ex < 100 || ex > 140) c1++;
    }
    atomicAdd(&cf, c1);
    __syncthreads();
    if (tid == 0) { flags[0] = (cf > 512) ? 1 : 0; flags[1] = i64m; }
  }
}

// ---------------------------------------------------------------------------
// scanperm: full-hist LDS scan per block; block 0 writes rowptr; each block
// permutes its 256 edges (perm+psrc). If do_copy: also writes the permuted
// bf16 edge row EVS[pos][76] = [edge_s(64) | edge_v(12)] (coalesced reads,
// row-contiguous scatter writes).
// ---------------------------------------------------------------------------
__global__ __launch_bounds__(256) void scanperm(
    const void* __restrict__ edge_index, const void* __restrict__ edge_s,
    const void* __restrict__ edge_v, const int* __restrict__ flags,
    const int* __restrict__ hist, int* __restrict__ rowptr,
    int* __restrict__ fill, int* __restrict__ perm, int* __restrict__ psrc,
    short* __restrict__ EVS, int do_copy)
{
  __shared__ int rp[N_NODES];
  __shared__ int part[256];
  __shared__ int posL[256];
  const int tid = threadIdx.x;
  for (int i = tid; i < N_NODES; i += 256) rp[i] = hist[i];
  __syncthreads();
  const int base = tid * 40;
  int s = 0;
  for (int i = 0; i < 40; ++i) { int idx = base + i; if (idx < N_NODES) s += rp[idx]; }
  part[tid] = s;
  __syncthreads();
  for (int off = 1; off < 256; off <<= 1) {
    int v = (tid >= off) ? part[tid - off] : 0;
    __syncthreads();
    part[tid] += v;
    __syncthreads();
  }
  int run = (tid > 0) ? part[tid - 1] : 0;
  for (int i = 0; i < 40; ++i) {
    int idx = base + i;
    if (idx < N_NODES) { int h = rp[idx]; rp[idx] = run; run += h; }
  }
  __syncthreads();
  if (blockIdx.x == 0) {
    for (int i = tid; i < N_NODES; i += 256) rowptr[i] = rp[i];
    if (tid == 0) rowptr[N_NODES] = part[255];
  }
  const int i64m = flags[1], f32m = flags[0];
  int e = blockIdx.x * 256 + tid;
  int dst = get_ei(edge_index, i64m, (long)E_TOT + e);
  int src = get_ei(edge_index, i64m, e);
  int pos = rp[dst] + atomicAdd(&fill[dst], 1);
  perm[pos] = e; psrc[pos] = src;
  posL[tid] = pos;
  __syncthreads();
  if (do_copy) {
    const long ebase = (long)blockIdx.x * 256;
    for (int i = tid; i < 256 * 76; i += 256) {
      int li = i / 76, ch = i - li * 76;
      long eg = ebase + li;
      float v = (ch < 64) ? ldin(edge_s, f32m, eg * 64 + ch)
                          : ldin(edge_v, f32m, eg * 12 + (ch - 64));
      EVS[(long)posL[li] * 76 + ch] = f2bf(v);
    }
  }
}

// ---------------------------------------------------------------------------
// node_pre_prep: b<2500 -> CN/QARR/QV/nsb per 4 nodes (weights in LDS);
// b in [2500,3172) -> Wbig prep; b==3172 -> whv4.
// ---------------------------------------------------------------------------
__global__ __launch_bounds__(256) void node_pre_prep(
    const void* __restrict__ node_v, const void* __restrict__ wh,
    const void* __restrict__ wv, const void* __restrict__ node_s,
    const void* __restrict__ ws_w, const int* __restrict__ flags,
    short* __restrict__ CN, short* __restrict__ QARR,
    short* __restrict__ QV, short* __restrict__ ns_bf,
    short* __restrict__ Wbig, float* __restrict__ whv4)
{
  const int f32m = flags[0];
  const int b = blockIdx.x, tid = threadIdx.x;
  __shared__ float whs[68 * 68];
  __shared__ float wvs[68 * 32];
  __shared__ float nv[4][96];
  __shared__ float pq[4][408];
  if (b >= 2500) {
    int pb = b - 2500;
    if (pb < 672) {
      int flat = pb * 256 + tid;           // = o*672 + k
      int o = flat / 672, k = flat % 672;
      short v = 0;
      if (k < 320)      v = f2bf(ldin(ws_w, f32m, (long)k * 256 + o));
      else if (k < 388) v = f2bf(ldin(ws_w, f32m, (long)(576 + k - 320) * 256 + o));
      else if (k >= 416) v = f2bf(ldin(ws_w, f32m, (long)(k - 96) * 256 + o));
      Wbig[flat] = v;
    } else if (tid < 128) {
      int q = tid / 32, c = tid % 32;
      float acc = 0.f;
      for (int h = 0; h < 68; ++h)
        acc += ldin(wh, f32m, (32 + q) * 68 + h) * ldin(wv, f32m, h * 32 + c);
      whv4[tid] = acc;
    }
    return;
  }
  int n0 = b * 4;
  for (int i = tid; i < 4624; i += 256) whs[i] = ldin(wh, f32m, i);
  for (int i = tid; i < 2176; i += 256) wvs[i] = ldin(wv, f32m, i);
  for (int i = tid; i < 4 * 96; i += 256) nv[i / 96][i % 96] = ldin(node_v, f32m, (long)n0 * 96 + i);
  for (int i = tid; i < 1024; i += 256)
    ns_bf[(long)n0 * 256 + i] = f2bf(ldin(node_s, f32m, (long)n0 * 256 + i));
  __syncthreads();
  for (int o = tid; o < 4 * 408; o += 256) {
    int i = o / 408, r0 = o % 408;
    int part = r0 / 204, r = r0 % 204, d = r / 68, h = r % 68;
    int cbase = part ? 36 : 0;
    float acc = 0.f;
#pragma unroll
    for (int c = 0; c < 32; ++c)
      acc += nv[i][c * 3 + d] * whs[(cbase + c) * 68 + h];
    pq[i][r0] = acc;
  }
  __syncthreads();
  // CN rows
  for (int o = tid; o < 4 * 544; o += 256) {
    int i = o / 544, k = o % 544;
    short v = 0;
    if (k < 512) {
      int l = k >> 3, j = k & 7;
      if (j < 4)      v = f2bf(ldin(node_s, f32m, (long)(n0 + i) * 256 + l * 4 + j));
      else if (j < 7) v = f2bf(pq[i][(j - 4) * 68 + l]);
    } else if (k < 528) {
      int idx = k - 512, jj = idx >> 2, d = idx & 3;
      if (d < 3) v = f2bf(pq[i][d * 68 + 64 + jj]);
    }
    CN[(long)(n0 + i) * 544 + k] = v;
  }
  // QARR rows
  for (int o = tid; o < 4 * 208; o += 256) {
    int i = o / 208, k = o % 208;
    QARR[(long)(n0 + i) * 208 + k] = (k < 204) ? f2bf(pq[i][204 + k]) : (short)0;
  }
  // QV
  for (int o = tid; o < 4 * 96; o += 256) {
    int i = o / 96, r = o % 96, d = r / 32, c = r % 32;
    float acc = 0.f;
    for (int h = 0; h < 68; ++h)
      acc += pq[i][204 + d * 68 + h] * wvs[h * 32 + c];
    QV[(long)(n0 + i) * 96 + r] = f2bf(acc);
  }
}

// ---------------------------------------------------------------------------
struct EdgeLds {
  float ansL[4][256];
  float apL[4][204];
  float avnL[4][132];
  float aesL[4][64];
  float aevL[4][12];
};

__device__ __forceinline__ void edge_reduce_epilogue(
    EdgeLds* lds, int n, int tid, int deg,
    short* __restrict__ ANSb, short* __restrict__ EAb,
    float* __restrict__ AP, float* __restrict__ AEV)
{
  __syncthreads();
  const float inv = 1.f / fmaxf((float)deg, 1.f);
  {
    float s = lds->ansL[0][tid] + lds->ansL[1][tid] + lds->ansL[2][tid] + lds->ansL[3][tid];
    ANSb[(long)n * 256 + tid] = f2bf(s * inv);
  }
  if (tid < 204) {
    float s = lds->apL[0][tid] + lds->apL[1][tid] + lds->apL[2][tid] + lds->apL[3][tid];
    AP[(long)n * 204 + tid] = s;
  } else if (tid < 216) {
    int c = tid - 204;
    float s = lds->aevL[0][c] + lds->aevL[1][c] + lds->aevL[2][c] + lds->aevL[3][c];
    AEV[(long)n * 12 + c] = s;
  }
  if (tid < 64) {
    float s = lds->aesL[0][tid] + lds->aesL[1][tid] + lds->aesL[2][tid] + lds->aesL[3][tid];
    EAb[(long)n * 160 + tid] = f2bf(s * inv);
  } else if (tid < 132) {
    int c = tid - 64;
    float s = lds->avnL[0][c] + lds->avnL[1][c] + lds->avnL[2][c] + lds->avnL[3][c];
    EAb[(long)n * 160 + 64 + c] = f2bf(s * inv);
  } else if (tid < 160) {
    EAb[(long)n * 160 + tid] = 0;
  }
}

// ---------------------------------------------------------------------------
// edge_block_seq: sequential bf16 edge rows (EVS, pos-ordered). Only gather
// left is the CN row per edge. No perm, no eid, dtype-independent loop.
// ---------------------------------------------------------------------------
__global__ __launch_bounds__(256) void edge_block_seq(
    const short* __restrict__ EVS, const void* __restrict__ wh,
    const int* __restrict__ flags, const int* __restrict__ rowptr,
    const int* __restrict__ psrc, const short* __restrict__ CN,
    const short* __restrict__ QARR,
    short* __restrict__ ANSb, short* __restrict__ EAb,
    float* __restrict__ AP, float* __restrict__ AEV)
{
  __shared__ EdgeLds lds;
  const int f32m = flags[0];
  const int tid = threadIdx.x, lane = tid & 63, w = tid >> 6;
  const int n = blockIdx.x;
  const int beg = rowptr[n], deg = rowptr[n + 1] - beg;
  const bool has2 = (lane < 4);
  const int h2 = 64 + lane;
  const float w4a0 = ldin(wh, f32m, 32 * 68 + lane);
  const float w4a1 = ldin(wh, f32m, 33 * 68 + lane);
  const float w4a2 = ldin(wh, f32m, 34 * 68 + lane);
  const float w4a3 = ldin(wh, f32m, 35 * 68 + lane);
  const float w4b0 = has2 ? ldin(wh, f32m, 32 * 68 + h2) : 0.f;
  const float w4b1 = has2 ? ldin(wh, f32m, 33 * 68 + h2) : 0.f;
  const float w4b2 = has2 ? ldin(wh, f32m, 34 * 68 + h2) : 0.f;
  const float w4b3 = has2 ? ldin(wh, f32m, 35 * 68 + h2) : 0.f;
  const short* qp = QARR + (long)n * 208;
  const float qa0 = bf(qp[0 * 68 + lane]);
  const float qa1 = bf(qp[1 * 68 + lane]);
  const float qa2 = bf(qp[2 * 68 + lane]);
  const float qb0 = has2 ? bf(qp[0 * 68 + h2]) : 0.f;
  const float qb1 = has2 ? bf(qp[1 * 68 + h2]) : 0.f;
  const float qb2 = has2 ? bf(qp[2 * 68 + h2]) : 0.f;
  float an0 = 0.f, an1 = 0.f, an2 = 0.f, an3 = 0.f;
  float ap0 = 0.f, ap1 = 0.f, ap2 = 0.f;
  float bq0 = 0.f, bq1 = 0.f, bq2 = 0.f;
  float avna = 0.f, avnb = 0.f, aes = 0.f, aev = 0.f;
  int e = w;
  int sv = (e < deg) ? psrc[beg + e] : 0;
  while (e < deg) {
    int en = e + 4;
    int svn = (en < deg) ? psrc[beg + en] : 0;   // prefetch next index
    const int s_s = __builtin_amdgcn_readfirstlane(sv);
    const int row = __builtin_amdgcn_readfirstlane(beg + e);
    const short* cs = CN + (long)s_s * 544;
    short8 cv = *(const short8*)(cs + lane * 8);
    const short* er = EVS + (long)row * 76;
    float esv = bf(er[lane]);
    float evl = (lane < 12) ? bf(er[64 + lane]) : 0.f;
    const unsigned* ep = (const unsigned*)(er + 64);
    unsigned u0 = ep[0], u1 = ep[1], u2 = ep[2];
    unsigned u3 = ep[3], u4 = ep[4], u5 = ep[5];
    float c0 = bflo(u0), c1 = bfhi(u0), c2 = bflo(u1), c3 = bfhi(u1);
    float c4 = bflo(u2), c5 = bfhi(u2), c6 = bflo(u3), c7 = bfhi(u3);
    float c8 = bflo(u4), c9 = bfhi(u4), cA = bflo(u5), cB = bfhi(u5);
    an0 += bf(cv[0]); an1 += bf(cv[1]); an2 += bf(cv[2]); an3 += bf(cv[3]);
    const float pa0 = bf(cv[4]), pa1 = bf(cv[5]), pa2 = bf(cv[6]);
    aes += esv; aev += evl;
    float v0 = pa0 + qa0 + c0 * w4a0 + c3 * w4a1 + c6 * w4a2 + c9 * w4a3;
    float v1 = pa1 + qa1 + c1 * w4a0 + c4 * w4a1 + c7 * w4a2 + cA * w4a3;
    float v2 = pa2 + qa2 + c2 * w4a0 + c5 * w4a1 + c8 * w4a2 + cB * w4a3;
    avna += sqrtf(fmaxf(v0 * v0 + v1 * v1 + v2 * v2, 1e-8f));
    ap0 += pa0; ap1 += pa1; ap2 += pa2;
    if (has2) {
      s16x4 tl = *(const s16x4*)(cs + 512 + lane * 4);
      const float pb0 = bf(tl.x), pb1 = bf(tl.y), pb2 = bf(tl.z);
      float t0 = pb0 + qb0 + c0 * w4b0 + c3 * w4b1 + c6 * w4b2 + c9 * w4b3;
      float t1 = pb1 + qb1 + c1 * w4b0 + c4 * w4b1 + c7 * w4b2 + cA * w4b3;
      float t2 = pb2 + qb2 + c2 * w4b0 + c5 * w4b1 + c8 * w4b2 + cB * w4b3;
      avnb += sqrtf(fmaxf(t0 * t0 + t1 * t1 + t2 * t2, 1e-8f));
      bq0 += pb0; bq1 += pb1; bq2 += pb2;
    }
    e = en; sv = svn;
  }
  lds.ansL[w][lane * 4 + 0] = an0; lds.ansL[w][lane * 4 + 1] = an1;
  lds.ansL[w][lane * 4 + 2] = an2; lds.ansL[w][lane * 4 + 3] = an3;
  lds.apL[w][lane * 3 + 0] = ap0; lds.apL[w][lane * 3 + 1] = ap1;
  lds.apL[w][lane * 3 + 2] = ap2;
  if (has2) {
    lds.apL[w][192 + lane * 3 + 0] = bq0;
    lds.apL[w][192 + lane * 3 + 1] = bq1;
    lds.apL[w][192 + lane * 3 + 2] = bq2;
  }
  lds.avnL[w][lane] = avna;
  if (has2) lds.avnL[w][64 + lane] = avnb;
  lds.aesL[w][lane] = aes;
  if (lane < 12) lds.aevL[w][lane] = aev;
  edge_reduce_epilogue(&lds, n, tid, deg, ANSb, EAb, AP, AEV);
}

// ---------------------------------------------------------------------------
// edge_block_fb: fallback (R7-proven body) when workspace can't hold EVS.
// ---------------------------------------------------------------------------
template <int F32M>
__device__ __forceinline__ void edge_body_fb(
    const void* __restrict__ edge_v, const void* __restrict__ edge_s,
    const void* __restrict__ wh,
    const int* __restrict__ rowptr, const int* __restrict__ perm,
    const int* __restrict__ psrc, const short* __restrict__ CN,
    const short* __restrict__ QARR,
    short* __restrict__ ANSb, short* __restrict__ EAb,
    float* __restrict__ AP, float* __restrict__ AEV, EdgeLds* lds)
{
  const int tid = threadIdx.x;
  const int lane = tid & 63, w = tid >> 6;
  const int n = blockIdx.x;
  const int beg = rowptr[n], deg = rowptr[n + 1] - beg;
  const bool has2 = (lane < 4);
  const int h2 = 64 + lane;
  const float w4a0 = ldin(wh, F32M, 32 * 68 + lane);
  const float w4a1 = ldin(wh, F32M, 33 * 68 + lane);
  const float w4a2 = ldin(wh, F32M, 34 * 68 + lane);
  const float w4a3 = ldin(wh, F32M, 35 * 68 + lane);
  const float w4b0 = has2 ? ldin(wh, F32M, 32 * 68 + h2) : 0.f;
  const float w4b1 = has2 ? ldin(wh, F32M, 33 * 68 + h2) : 0.f;
  const float w4b2 = has2 ? ldin(wh, F32M, 34 * 68 + h2) : 0.f;
  const float w4b3 = has2 ? ldin(wh, F32M, 35 * 68 + h2) : 0.f;
  const short* qp = QARR + (long)n * 208;
  const float qa0 = bf(qp[0 * 68 + lane]);
  const float qa1 = bf(qp[1 * 68 + lane]);
  const float qa2 = bf(qp[2 * 68 + lane]);
  const float qb0 = has2 ? bf(qp[0 * 68 + h2]) : 0.f;
  const float qb1 = has2 ? bf(qp[1 * 68 + h2]) : 0.f;
  const float qb2 = has2 ? bf(qp[2 * 68 + h2]) : 0.f;
  float an0 = 0.f, an1 = 0.f, an2 = 0.f, an3 = 0.f;
  float ap0 = 0.f, ap1 = 0.f, ap2 = 0.f;
  float bq0 = 0.f, bq1 = 0.f, bq2 = 0.f;
  float avna = 0.f, avnb = 0.f, aes = 0.f, aev = 0.f;
  int e = w;
  int sv = 0, eid = 0;
  if (e < deg) { sv = psrc[beg + e]; eid = perm[beg + e]; }
  while (e < deg) {
    int en = e + 4, svn = 0, eidn = 0;
    if (en < deg) { svn = psrc[beg + en]; eidn = perm[beg + en]; }
    const int sv_s  = __builtin_amdgcn_readfirstlane(sv);
    const int eid_s = __builtin_amdgcn_readfirstlane(eid);
    float ev0, ev1, ev2, ev3, ev4, ev5, ev6, ev7, ev8, ev9, evA, evB;
    if (F32M) {
      const float* evp = (const float*)edge_v + (long)eid_s * 12;
      ev0 = evp[0]; ev1 = evp[1]; ev2 = evp[2]; ev3 = evp[3];
      ev4 = evp[4]; ev5 = evp[5]; ev6 = evp[6]; ev7 = evp[7];
      ev8 = evp[8]; ev9 = evp[9]; evA = evp[10]; evB = evp[11];
    } else {
      const unsigned* evp = (const unsigned*)((const short*)edge_v + (long)eid_s * 12);
      unsigned u0 = evp[0], u1 = evp[1], u2 = evp[2];
      unsigned u3 = evp[3], u4 = evp[4], u5 = evp[5];
      ev0 = bflo(u0); ev1 = bfhi(u0); ev2 = bflo(u1); ev3 = bfhi(u1);
      ev4 = bflo(u2); ev5 = bfhi(u2); ev6 = bflo(u3); ev7 = bfhi(u3);
      ev8 = bflo(u4); ev9 = bfhi(u4); evA = bflo(u5); evB = bfhi(u5);
    }
    const short* cs = CN + (long)sv_s * 544;
    short8 cv = *(const short8*)(cs + lane * 8);
    an0 += bf(cv[0]); an1 += bf(cv[1]); an2 += bf(cv[2]); an3 += bf(cv[3]);
    const float pa0 = bf(cv[4]), pa1 = bf(cv[5]), pa2 = bf(cv[6]);
    aes += ldin(edge_s, F32M, (long)eid_s * 64 + lane);
    if (lane < 12) aev += ldin(edge_v, F32M, (long)eid_s * 12 + lane);
    float v0 = pa0 + qa0 + ev0 * w4a0 + ev3 * w4a1 + ev6 * w4a2 + ev9 * w4a3;
    float v1 = pa1 + qa1 + ev1 * w4a0 + ev4 * w4a1 + ev7 * w4a2 + evA * w4a3;
    float v2 = pa2 + qa2 + ev2 * w4a0 + ev5 * w4a1 + ev8 * w4a2 + evB * w4a3;
    avna += sqrtf(fmaxf(v0 * v0 + v1 * v1 + v2 * v2, 1e-8f));
    ap0 += pa0; ap1 += pa1; ap2 += pa2;
    if (has2) {
      s16x4 p2 = *(const s16x4*)(cs + 512 + lane * 4);
      const float pb0 = bf(p2.x), pb1 = bf(p2.y), pb2 = bf(p2.z);
      float u0 = pb0 + qb0 + ev0 * w4b0 + ev3 * w4b1 + ev6 * w4b2 + ev9 * w4b3;
      float u1 = pb1 + qb1 + ev1 * w4b0 + ev4 * w4b1 + ev7 * w4b2 + evA * w4b3;
      float u2 = pb2 + qb2 + ev2 * w4b0 + ev5 * w4b1 + ev8 * w4b2 + evB * w4b3;
      avnb += sqrtf(fmaxf(u0 * u0 + u1 * u1 + u2 * u2, 1e-8f));
      bq0 += pb0; bq1 += pb1; bq2 += pb2;
    }
    e = en; sv = svn; eid = eidn;
  }
  lds->ansL[w][lane * 4 + 0] = an0; lds->ansL[w][lane * 4 + 1] = an1;
  lds->ansL[w][lane * 4 + 2] = an2; lds->ansL[w][lane * 4 + 3] = an3;
  lds->apL[w][lane * 3 + 0] = ap0; lds->apL[w][lane * 3 + 1] = ap1;
  lds->apL[w][lane * 3 + 2] = ap2;
  if (has2) {
    lds->apL[w][192 + lane * 3 + 0] = bq0;
    lds->apL[w][192 + lane * 3 + 1] = bq1;
    lds->apL[w][192 + lane * 3 + 2] = bq2;
  }
  lds->avnL[w][lane] = avna;
  if (has2) lds->avnL[w][64 + lane] = avnb;
  lds->aesL[w][lane] = aes;
  if (lane < 12) lds->aevL[w][lane] = aev;
  edge_reduce_epilogue(lds, n, tid, deg, ANSb, EAb, AP, AEV);
}

__global__ __launch_bounds__(256) void edge_block_fb(
    const void* __restrict__ edge_v, const void* __restrict__ edge_s,
    const void* __restrict__ wh, const int* __restrict__ flags,
    const int* __restrict__ rowptr, const int* __restrict__ perm,
    const int* __restrict__ psrc, const short* __restrict__ CN,
    const short* __restrict__ QARR,
    short* __restrict__ ANSb, short* __restrict__ EAb,
    float* __restrict__ AP, float* __restrict__ AEV)
{
  __shared__ EdgeLds lds;
  if (flags[0])
    edge_body_fb<1>(edge_v, edge_s, wh, rowptr, perm, psrc, CN, QARR,
                    ANSb, EAb, AP, AEV, &lds);
  else
    edge_body_fb<0>(edge_v, edge_s, wh, rowptr, perm, psrc, CN, QARR,
                    ANSb, EAb, AP, AEV, &lds);
}

// ---------------------------------------------------------------------------
// node_gemm: NodeS[n] = [ANS/deg | AES/deg|AVN/deg | ns] @ Wbig
// ---------------------------------------------------------------------------
__global__ __launch_bounds__(256) void node_gemm(
    const short* __restrict__ ANSb, const short* __restrict__ EAb,
    const short* __restrict__ nsb, const short* __restrict__ Wbig,
    float* __restrict__ NodeS)
{
  __shared__ __align__(16) short Xs[64 * 40];
  __shared__ __align__(16) short Ws[256 * 40];
  const int tid = threadIdx.x;
  const int n0 = blockIdx.x * 64;
  const int lane = tid & 63, wave = tid >> 6;
  const int frow = lane & 15, fk = (lane >> 4) * 8, q = lane >> 4;
  f32x4 acc[4][4];
#pragma unroll
  for (int ri = 0; ri < 4; ++ri)
#pragma unroll
    for (int ci = 0; ci < 4; ++ci)
      acc[ri][ci] = (f32x4){0.f, 0.f, 0.f, 0.f};
  const int se = tid >> 2, sq = tid & 3;
  const int rn = min(n0 + se, N_NODES - 1);
  for (int s = 0; s < 21; ++s) {
    short8 xv;
    if (s < 8)       xv = *(const short8*)&ANSb[(long)rn * 256 + s * 32 + sq * 8];
    else if (s < 13) xv = *(const short8*)&EAb[(long)rn * 160 + (s - 8) * 32 + sq * 8];
    else             xv = *(const short8*)&nsb[(long)rn * 256 + (s - 13) * 32 + sq * 8];
    *(short8*)&Xs[se * 40 + sq * 8] = xv;
#pragma unroll
    for (int it = 0; it < 4; ++it) {
      int flat = it * 256 + tid;
      int nn = flat >> 2, qq = flat & 3;
      *(short8*)&Ws[nn * 40 + qq * 8] = *(const short8*)&Wbig[nn * 672 + s * 32 + qq * 8];
    }
    __syncthreads();
    short8 a[4];
#pragma unroll
    for (int ri = 0; ri < 4; ++ri)
      a[ri] = *(const short8*)&Xs[(ri * 16 + frow) * 40 + fk];
#pragma unroll
    for (int ci = 0; ci < 4; ++ci) {
      int nn = wave * 64 + ci * 16 + frow;
      short8 b = *(const short8*)&Ws[nn * 40 + fk];
#pragma unroll
      for (int ri = 0; ri < 4; ++ri)
        acc[ri][ci] = __builtin_amdgcn_mfma_f32_16x16x32_bf16(a[ri], b, acc[ri][ci], 0, 0, 0);
    }
    __syncthreads();
  }
#pragma unroll
  for (int ri = 0; ri < 4; ++ri)
#pragma unroll
    for (int rr = 0; rr < 4; ++rr) {
      int row = n0 + ri * 16 + q * 4 + rr;
      if (row < N_NODES) {
#pragma unroll
        for (int ci = 0; ci < 4; ++ci) {
          int col = wave * 64 + ci * 16 + (lane & 15);
          NodeS[(long)row * 256 + col] = acc[ri][ci][rr];
        }
      }
    }
}

// ---------------------------------------------------------------------------
// final_fuse: per 4 nodes — agg_v = AP@wv + AEV@whv4 in LDS, then write all
// 4*352 outputs.
// ---------------------------------------------------------------------------
__global__ __launch_bounds__(256) void final_fuse(
    const float* __restrict__ NodeS, const float* __restrict__ AP,
    const float* __restrict__ AEV, const void* __restrict__ wv,
    const float* __restrict__ whv4, const int* __restrict__ rowptr,
    const short* __restrict__ QV, const void* __restrict__ ws_b,
    const int* __restrict__ flags, void* __restrict__ out)
{
  const int f32m = flags[0];
  int n0 = blockIdx.x * 4, tid = threadIdx.x;
  __shared__ float wvs[68 * 32];
  __shared__ float wh4s[128];
  __shared__ float APs[4][204];
  __shared__ float AEVs[4][12];
  __shared__ float aggL[4][96];
  for (int i = tid; i < 2176; i += 256) wvs[i] = ldin(wv, f32m, i);
  if (tid < 128) wh4s[tid] = whv4[tid];
  for (int i = tid; i < 816; i += 256) APs[i / 204][i % 204] = AP[(long)n0 * 204 + i];
  if (tid < 48) AEVs[tid / 12][tid % 12] = AEV[(long)n0 * 12 + tid];
  __syncthreads();
  for (int o = tid; o < 384; o += 256) {
    int i = o / 96, r = o % 96, c = r / 3, d = r % 3;
    float acc = AEVs[i][d] * wh4s[c] + AEVs[i][3 + d] * wh4s[32 + c]
              + AEVs[i][6 + d] * wh4s[64 + c] + AEVs[i][9 + d] * wh4s[96 + c];
    for (int h = 0; h < 68; ++h)
      acc += APs[i][h * 3 + d] * wvs[h * 32 + c];
    aggL[i][r] = acc;
  }
  __syncthreads();
  for (int o = tid; o < 1408; o += 256) {
    int i = o / 352, j = o % 352;
    int n = n0 + i;
    int deg = rowptr[n + 1] - rowptr[n];
    float v;
    if (j < 256) {
      v = (deg > 0) ? (NodeS[(long)n * 256 + j] + ldin(ws_b, f32m, j)) : 0.f;
    } else {
      int m = j - 256, ch = m / 3, d = m % 3;
      float inv = 1.f / fmaxf((float)deg, 1.f);
      v = aggL[i][m] * inv;
      if (deg > 0) v += bf(QV[(long)n * 96 + d * 32 + ch]);
    }
    long flat = (long)n * 352 + j;
    if (f32m) ((float*)out)[flat] = v;
    else      ((__hip_bfloat16*)out)[flat] = __float2bfloat16(v);
  }
}

extern "C" void kernel_launch(void* const* d_in, const int* in_sizes, int n_in,
                              void* d_out, int out_size, void* d_ws, size_t ws_size,
                              hipStream_t stream) {
  const void* node_s = d_in[0];
  const void* node_v = d_in[1];
  const void* edge_s = d_in[2];
  const void* edge_v = d_in[3];
  const void* wh     = d_in[4];
  const void* ws_w   = d_in[5];
  const void* ws_b   = d_in[6];
  const void* wv     = d_in[7];
  const void* edge_index = d_in[8];

  char* ws = (char*)d_ws;
  int*   hist  = (int*)(ws + HIST_OFF);
  int*   fill  = (int*)(ws + FILL_OFF);
  int*   rowptr= (int*)(ws + ROWPTR_OFF);
  int*   perm  = (int*)(ws + PERM_OFF);
  int*   psrc  = (int*)(ws + PSRC_OFF);
  short* CN    = (short*)(ws + CN_OFF);
  short* QARR  = (short*)(ws + QARR_OFF);
  short* QV    = (short*)(ws + QV_OFF);
  float* whv4  = (float*)(ws + WHV4_OFF);
  short* Wbig  = (short*)(ws + WBIG_OFF);
  short* ns_bf = (short*)(ws + NSBF_OFF);
  short* ANSb  = (short*)(ws + ANSB_OFF);
  short* EAb   = (short*)(ws + EAB_OFF);
  float* AP    = (float*)(ws + AP_OFF);
  float* AEV   = (float*)(ws + AEV_OFF);
  float* NodeS = (float*)(ws + NODES_OFF);
  int*   flags = (int*)(ws + FLAGS_OFF);
  short* EVS   = (short*)(ws + EVS_OFF);

  const int do_copy = (ws_size >= (size_t)EVS_OFF + (size_t)EVS_BYTES) ? 1 : 0;

  hipMemsetAsync(d_ws, 0, ZERO_BYTES, stream);
  hist_det<<<1250, 256, 0, stream>>>(edge_index, (const unsigned short*)node_s,
                                     hist, flags);
  scanperm<<<1250, 256, 0, stream>>>(edge_index, edge_s, edge_v, flags, hist,
                                     rowptr, fill, perm, psrc, EVS, do_copy);
  node_pre_prep<<<3173, 256, 0, stream>>>(node_v, wh, wv, node_s, ws_w, flags,
                                          CN, QARR, QV, ns_bf, Wbig, whv4);
  if (do_copy)
    edge_block_seq<<<10000, 256, 0, stream>>>(EVS, wh, flags, rowptr, psrc,
                                              CN, QARR, ANSb, EAb, AP, AEV);
  else
    edge_block_fb<<<10000, 256, 0, stream>>>(edge_v, edge_s, wh, flags, rowptr,
                                             perm, psrc, CN, QARR,
                                             ANSb, EAb, AP, AEV);
  node_gemm<<<157, 256, 0, stream>>>(ANSb, EAb, ns_bf, Wbig, NodeS);
  final_fuse<<<2500, 256, 0, stream>>>(NodeS, AP, AEV, wv, whv4, rowptr,
                                       QV, ws_b, flags, d_out);
}